// Round 1
// baseline (359.207 us; speedup 1.0000x reference)
//
#include <hip/hip_runtime.h>

// CTC greedy search:  logits (T,N,V) fp32, in_lens (N) int32.
// Outputs (all fp32, concatenated): max_total (N), paths (T,N), out_lens (N).

#define WAVE 64

typedef float fvec4 __attribute__((ext_vector_type(4)));
typedef int   ivec4 __attribute__((ext_vector_type(4)));

// ---------------- Kernel 1: per-(t,n) row logsumexp-max + argmax -------------
// One wave per row of V elements, wave-independent grid-stride (no block
// coupling, no LDS, no barriers).  V = CH*256 held in registers (CH fvec4 per
// lane) so HBM is touched exactly once.  Results stored TRANSPOSED for
// kernel 2: rmaxT[n*T + t], rargT[n*T + t]  (row = t*N + n).
// Also writes the default path value out_paths[row] = argmax (row is exactly
// the flat (T,N) index); the 4B scatters land in a 256 KB region -> L2 merges.
template <int CH>
__global__ __launch_bounds__(256) void row_lse_kernel(
    const float* __restrict__ logits,
    float* __restrict__ rmaxT, int* __restrict__ rargT,
    float* __restrict__ out_paths,
    int T, int N, int rows) {
  const int lane = threadIdx.x & (WAVE - 1);
  const int w    = threadIdx.x >> 6;            // wave id in block (0..3)
  const int V = CH * 256;
  const int wstride = gridDim.x * 4;            // waves in grid

  for (int row = blockIdx.x * 4 + w; row < rows; row += wstride) {
    const fvec4* p4 = (const fvec4*)(logits + (size_t)row * V);

    float m = -3.4e38f;
    int   mi = 0;
    fvec4 v[CH];
#pragma unroll
    for (int c = 0; c < CH; ++c) {
      v[c] = p4[c * 64 + lane];                 // 16B/lane, 1KB/wave-instr
      const int idx = c * 256 + lane * 4;
      if (v[c].x > m) { m = v[c].x; mi = idx; }
      if (v[c].y > m) { m = v[c].y; mi = idx + 1; }
      if (v[c].z > m) { m = v[c].z; mi = idx + 2; }
      if (v[c].w > m) { m = v[c].w; mi = idx + 3; }
    }
    // wave reduce: max value, first (lowest) index on ties
#pragma unroll
    for (int off = 32; off; off >>= 1) {
      const float om = __shfl_down(m, off);
      const int   oi = __shfl_down(mi, off);
      if (om > m || (om == m && oi < mi)) { m = om; mi = oi; }
    }
    m = __shfl(m, 0);  // broadcast row max to all lanes

    float s = 0.f;
#pragma unroll
    for (int c = 0; c < CH; ++c)
      s += __expf(v[c].x - m) + __expf(v[c].y - m) +
           __expf(v[c].z - m) + __expf(v[c].w - m);
#pragma unroll
    for (int off = 32; off; off >>= 1) s += __shfl_down(s, off);

    if (lane == 0) {
      const int t = row / N, n = row % N;
      // max(log_softmax) = max - lse = -log(sum exp(x - max))
      rmaxT[(size_t)n * T + t] = -__logf(s);
      rargT[(size_t)n * T + t] = mi;
      out_paths[row] = (float)mi;
    }
  }
}

// Generic fallback (any V): strided row scan, same grid-stride structure.
__global__ __launch_bounds__(256) void row_lse_generic(
    const float* __restrict__ logits,
    float* __restrict__ rmaxT, int* __restrict__ rargT,
    float* __restrict__ out_paths,
    int T, int N, int V, int rows) {
  const int lane = threadIdx.x & (WAVE - 1);
  const int w    = threadIdx.x >> 6;
  const int wstride = gridDim.x * 4;

  for (int row = blockIdx.x * 4 + w; row < rows; row += wstride) {
    const float* p = logits + (size_t)row * V;

    float m = -3.4e38f; int mi = 0;
    for (int i = lane; i < V; i += WAVE) {
      const float x = p[i];
      if (x > m) { m = x; mi = i; }
    }
    for (int off = 32; off; off >>= 1) {
      const float om = __shfl_down(m, off);
      const int   oi = __shfl_down(mi, off);
      if (om > m || (om == m && oi < mi)) { m = om; mi = oi; }
    }
    m = __shfl(m, 0);
    float s = 0.f;
    for (int i = lane; i < V; i += WAVE) s += __expf(p[i] - m);
    for (int off = 32; off; off >>= 1) s += __shfl_down(s, off);

    if (lane == 0) {
      const int t = row / N, n = row % N;
      rmaxT[(size_t)n * T + t] = -__logf(s);
      rargT[(size_t)n * T + t] = mi;
      out_paths[row] = (float)mi;
    }
  }
}

// ---------------- Kernel 2: per-n dedup + compaction + sums ------------------
// Default path values were already written by kernel 1; this kernel computes
// keep flags, the block scan, the two per-n scalars, and scatters only the
// kept tokens over the compacted prefix (masked_scatter_ semantics).
#define CB 256

// Fast path: T == CB * ITEMS, ITEMS % 4 == 0.  Vectorized loads, everything
// register-resident (no global re-read in the scatter pass), cross-thread
// prev via LDS.
template <int ITEMS>
__global__ __launch_bounds__(CB) void ctc_compact_fast(
    const float* __restrict__ rmaxT, const int* __restrict__ rargT,
    const int* __restrict__ in_lens, float* __restrict__ out,
    int T, int N, int V) {
  const int n = blockIdx.x;
  const int tid = threadIdx.x;
  const int L = in_lens[n];
  const int blank = V - 1;            // (-1 + V) % V
  const int t0 = tid * ITEMS;

  float* out_total = out;
  float* out_paths = out + N;                    // (T, N) layout
  float* out_lens  = out + N + (size_t)T * N;

  const float* rm = rmaxT + (size_t)n * T;
  const int*   ra = rargT + (size_t)n * T;

  int   a[ITEMS];
  float mv[ITEMS];
#pragma unroll
  for (int i = 0; i < ITEMS; i += 4) {
    *(ivec4*)(a + i)  = *(const ivec4*)(ra + t0 + i);
    *(fvec4*)(mv + i) = *(const fvec4*)(rm + t0 + i);
  }

  __shared__ int   s_last[CB];
  __shared__ int   s_cnt[CB];
  __shared__ float s_sum[CB];
  s_last[tid] = a[ITEMS - 1];
  __syncthreads();
  int prev = (tid > 0) ? s_last[tid - 1] : -1;   // argmax >= 0, so -1 != any

  bool keep[ITEMS];
  int   cnt = 0;
  float sum = 0.f;
#pragma unroll
  for (int i = 0; i < ITEMS; ++i) {
    const int t = t0 + i;
    keep[i] = (t < L) && (a[i] != blank) && (a[i] != prev);
    prev = a[i];
    cnt += keep[i] ? 1 : 0;
    sum += (t < L) ? mv[i] : 0.f;
  }

  s_cnt[tid] = cnt;
  s_sum[tid] = sum;
  __syncthreads();
  // inclusive Hillis-Steele scan (cnt) / reduction (sum rides along)
  for (int off = 1; off < CB; off <<= 1) {
    const int   c  = (tid >= off) ? s_cnt[tid - off] : 0;
    const float sv = (tid >= off) ? s_sum[tid - off] : 0.f;
    __syncthreads();
    s_cnt[tid] += c;
    s_sum[tid] += sv;
    __syncthreads();
  }
  if (tid == 0) {
    out_total[n] = s_sum[CB - 1];
    out_lens[n]  = (float)s_cnt[CB - 1];
  }

  // scatter kept tokens into compacted prefix (overwrites kernel-1 defaults;
  // cross-kernel ordering on the stream guarantees kernel 1 finished)
  int pos = s_cnt[tid] - cnt;                    // exclusive prefix
#pragma unroll
  for (int i = 0; i < ITEMS; ++i) {
    if (keep[i]) {
      out_paths[(size_t)pos * N + n] = (float)a[i];
      ++pos;
    }
  }
}

// Generic fallback (any T): original two-pass structure.
__global__ __launch_bounds__(CB) void ctc_compact_kernel(
    const float* __restrict__ rmaxT, const int* __restrict__ rargT,
    const int* __restrict__ in_lens, float* __restrict__ out,
    int T, int N, int V) {
  const int n = blockIdx.x;
  const int tid = threadIdx.x;
  const int L = in_lens[n];
  const int blank = V - 1;
  const int items = (T + CB - 1) / CB;
  const int t0 = tid * items;

  float* out_total = out;
  float* out_paths = out + N;
  float* out_lens  = out + N + (size_t)T * N;

  const float* rm = rmaxT + (size_t)n * T;
  const int*   ra = rargT + (size_t)n * T;

  int   cnt = 0;
  float sum = 0.f;
  int prev = (t0 > 0 && t0 <= T) ? ra[t0 - 1] : -1;
  for (int i = 0; i < items; ++i) {
    const int t = t0 + i;
    if (t >= T) break;
    const int a = ra[t];
    const bool keep = (t < L) && (a != blank) && (t == 0 || a != prev);
    prev = a;
    cnt += keep ? 1 : 0;
    if (t < L) sum += rm[t];
  }

  __shared__ int   s_cnt[CB];
  __shared__ float s_sum[CB];
  s_cnt[tid] = cnt;
  s_sum[tid] = sum;
  __syncthreads();
  for (int off = 1; off < CB; off <<= 1) {
    const int   c  = (tid >= off) ? s_cnt[tid - off] : 0;
    const float sv = (tid >= off) ? s_sum[tid - off] : 0.f;
    __syncthreads();
    s_cnt[tid] += c;
    s_sum[tid] += sv;
    __syncthreads();
  }
  const int prefix = s_cnt[tid] - cnt;
  if (tid == 0) {
    out_total[n] = s_sum[CB - 1];
    out_lens[n]  = (float)s_cnt[CB - 1];
  }

  int pos = prefix;
  prev = (t0 > 0 && t0 <= T) ? ra[t0 - 1] : -1;
  for (int i = 0; i < items; ++i) {
    const int t = t0 + i;
    if (t >= T) break;
    const int a = ra[t];
    const bool keep = (t < L) && (a != blank) && (t == 0 || a != prev);
    prev = a;
    if (keep) {
      out_paths[(size_t)pos * N + n] = (float)a;
      ++pos;
    }
  }
}

extern "C" void kernel_launch(void* const* d_in, const int* in_sizes, int n_in,
                              void* d_out, int out_size, void* d_ws, size_t ws_size,
                              hipStream_t stream) {
  const float* logits = (const float*)d_in[0];
  const int* in_lens  = (const int*)d_in[1];
  float* out = (float*)d_out;

  const int N = in_sizes[1];
  const int T = (out_size - 2 * N) / N;          // out = N + T*N + N
  const long long total = in_sizes[0];
  const int V = (int)(total / ((long long)T * N));
  const int rows = T * N;

  float* rmaxT = (float*)d_ws;
  int*   rargT = (int*)((char*)d_ws + (size_t)rows * sizeof(float));
  float* out_paths = out + N;

  int grid1 = (rows + 3) / 4;                    // 4 waves (rows) per block
  if (grid1 > 2048) grid1 = 2048;                // grid-stride persistent waves

  if (V == 1024) {
    row_lse_kernel<4><<<grid1, 256, 0, stream>>>(logits, rmaxT, rargT, out_paths, T, N, rows);
  } else if (V == 512) {
    row_lse_kernel<2><<<grid1, 256, 0, stream>>>(logits, rmaxT, rargT, out_paths, T, N, rows);
  } else if (V == 2048) {
    row_lse_kernel<8><<<grid1, 256, 0, stream>>>(logits, rmaxT, rargT, out_paths, T, N, rows);
  } else {
    row_lse_generic<<<grid1, 256, 0, stream>>>(logits, rmaxT, rargT, out_paths, T, N, V, rows);
  }

  if (T == CB * 8) {
    ctc_compact_fast<8><<<N, CB, 0, stream>>>(rmaxT, rargT, in_lens, out, T, N, V);
  } else {
    ctc_compact_kernel<<<N, CB, 0, stream>>>(rmaxT, rargT, in_lens, out, T, N, V);
  }
}

// Round 2
// 332.816 us; speedup vs baseline: 1.0793x; 1.0793x over previous
//
#include <hip/hip_runtime.h>

// CTC greedy search:  logits (T,N,V) fp32, in_lens (N) int32.
// Outputs (all fp32, concatenated): max_total (N), paths (T,N), out_lens (N).

#define WAVE 64

typedef float fvec4 __attribute__((ext_vector_type(4)));
typedef int   ivec4 __attribute__((ext_vector_type(4)));

// Fused per-row result: one 8B store instead of two scattered 4B stores.
struct alignas(8) MA { float m; int a; };

// ---------------- Kernel 1: per-(t,n) row logsumexp-max + argmax -------------
// One wave per TWO rows (independent interleaved chains): 8 dwordx4 loads
// issue up-front, then two independent scan/shuffle-reduce chains overlap.
// One-shot blocks (no grid-stride): HW block scheduler refills CU slots as
// blocks retire -> fresh loads issue immediately (free pipelining).
// Math is bit-identical to the verified round-0 kernel (same scan order,
// same reduce tree, same tie-breaks).
// Results stored transposed for kernel 2: rpairT[n*T + t] = {-log(s), argmax}.
// Default path value out_paths[row] = argmax written coalesced via LDS.
template <int CH>
__global__ __launch_bounds__(256, 8) void row_lse_kernel(
    const float* __restrict__ logits,
    MA* __restrict__ rpairT,
    float* __restrict__ out_paths,
    int T, int N, int rows) {
  const int lane = threadIdx.x & (WAVE - 1);
  const int w    = threadIdx.x >> 6;            // wave id in block (0..3)
  const int V = CH * 256;
  const int rowA = blockIdx.x * 8 + w * 2;
  const int rowB = rowA + 1;
  const bool aA = rowA < rows, aB = rowB < rows;
  const fvec4* pA = (const fvec4*)(logits + (size_t)(aA ? rowA : 0) * V);
  const fvec4* pB = (const fvec4*)(logits + (size_t)(aB ? rowB : 0) * V);

  fvec4 vA[CH], vB[CH];
#pragma unroll
  for (int c = 0; c < CH; ++c) {
    // streamed once -> nontemporal, keep L2/L3 for the small intermediates
    vA[c] = __builtin_nontemporal_load(pA + c * 64 + lane);
    vB[c] = __builtin_nontemporal_load(pB + c * 64 + lane);
  }

  float mA = -3.4e38f, mB = -3.4e38f;
  int   iA = 0,        iB = 0;
#pragma unroll
  for (int c = 0; c < CH; ++c) {
    const int idx = c * 256 + lane * 4;
    if (vA[c].x > mA) { mA = vA[c].x; iA = idx; }
    if (vA[c].y > mA) { mA = vA[c].y; iA = idx + 1; }
    if (vA[c].z > mA) { mA = vA[c].z; iA = idx + 2; }
    if (vA[c].w > mA) { mA = vA[c].w; iA = idx + 3; }
    if (vB[c].x > mB) { mB = vB[c].x; iB = idx; }
    if (vB[c].y > mB) { mB = vB[c].y; iB = idx + 1; }
    if (vB[c].z > mB) { mB = vB[c].z; iB = idx + 2; }
    if (vB[c].w > mB) { mB = vB[c].w; iB = idx + 3; }
  }
  // wave reduce: max value, first (lowest) index on ties. Two independent
  // chains interleaved -> shuffle latency of one hides under the other.
#pragma unroll
  for (int off = 32; off; off >>= 1) {
    const float omA = __shfl_down(mA, off);
    const int   oiA = __shfl_down(iA, off);
    const float omB = __shfl_down(mB, off);
    const int   oiB = __shfl_down(iB, off);
    if (omA > mA || (omA == mA && oiA < iA)) { mA = omA; iA = oiA; }
    if (omB > mB || (omB == mB && oiB < iB)) { mB = omB; iB = oiB; }
  }
  mA = __shfl(mA, 0);  // broadcast row max to all lanes
  mB = __shfl(mB, 0);

  float sA = 0.f, sB = 0.f;
#pragma unroll
  for (int c = 0; c < CH; ++c) {
    sA += __expf(vA[c].x - mA) + __expf(vA[c].y - mA) +
          __expf(vA[c].z - mA) + __expf(vA[c].w - mA);
    sB += __expf(vB[c].x - mB) + __expf(vB[c].y - mB) +
          __expf(vB[c].z - mB) + __expf(vB[c].w - mB);
  }
#pragma unroll
  for (int off = 32; off; off >>= 1) {
    sA += __shfl_down(sA, off);
    sB += __shfl_down(sB, off);
  }

  __shared__ float s_path[8];
  if (lane == 0) {
    if (aA) {
      const int t = rowA / N, n = rowA % N;
      // max(log_softmax) = max - lse = -log(sum exp(x - max))
      MA r; r.m = -__logf(sA); r.a = iA;
      rpairT[(size_t)n * T + t] = r;
      s_path[w * 2] = (float)iA;
    }
    if (aB) {
      const int t = rowB / N, n = rowB % N;
      MA r; r.m = -__logf(sB); r.a = iB;
      rpairT[(size_t)n * T + t] = r;
      s_path[w * 2 + 1] = (float)iB;
    }
  }
  __syncthreads();
  if (threadIdx.x < 8) {
    const int r = blockIdx.x * 8 + threadIdx.x;
    if (r < rows) out_paths[r] = s_path[threadIdx.x];
  }
}

// Generic fallback (any V): strided row scan, one row per wave, one-shot.
__global__ __launch_bounds__(256) void row_lse_generic(
    const float* __restrict__ logits,
    MA* __restrict__ rpairT,
    float* __restrict__ out_paths,
    int T, int N, int V, int rows) {
  const int lane = threadIdx.x & (WAVE - 1);
  const int w    = threadIdx.x >> 6;
  const int row  = blockIdx.x * 4 + w;
  const bool active = row < rows;
  const float* p = logits + (size_t)(active ? row : 0) * V;

  float m = -3.4e38f; int mi = 0;
  for (int i = lane; i < V; i += WAVE) {
    const float x = p[i];
    if (x > m) { m = x; mi = i; }
  }
  for (int off = 32; off; off >>= 1) {
    const float om = __shfl_down(m, off);
    const int   oi = __shfl_down(mi, off);
    if (om > m || (om == m && oi < mi)) { m = om; mi = oi; }
  }
  m = __shfl(m, 0);
  float s = 0.f;
  for (int i = lane; i < V; i += WAVE) s += __expf(p[i] - m);
  for (int off = 32; off; off >>= 1) s += __shfl_down(s, off);

  __shared__ float s_path[4];
  if (lane == 0 && active) {
    const int t = row / N, n = row % N;
    MA r; r.m = -__logf(s); r.a = mi;
    rpairT[(size_t)n * T + t] = r;
    s_path[w] = (float)mi;
  }
  __syncthreads();
  if (threadIdx.x < 4) {
    const int r = blockIdx.x * 4 + threadIdx.x;
    if (r < rows) out_paths[r] = s_path[threadIdx.x];
  }
}

// ---------------- Kernel 2: per-n dedup + compaction + sums ------------------
// Default path values were already written by kernel 1; this kernel computes
// keep flags, the block scan, the two per-n scalars, and scatters only the
// kept tokens over the compacted prefix (masked_scatter_ semantics).
#define CB 256

// Fast path: T == CB * ITEMS, ITEMS even.  Vectorized pair loads, everything
// register-resident (no global re-read in the scatter pass), cross-thread
// prev via LDS.
template <int ITEMS>
__global__ __launch_bounds__(CB) void ctc_compact_fast(
    const MA* __restrict__ rpairT,
    const int* __restrict__ in_lens, float* __restrict__ out,
    int T, int N, int V) {
  const int n = blockIdx.x;
  const int tid = threadIdx.x;
  const int L = in_lens[n];
  const int blank = V - 1;            // (-1 + V) % V
  const int t0 = tid * ITEMS;

  float* out_total = out;
  float* out_paths = out + N;                    // (T, N) layout
  float* out_lens  = out + N + (size_t)T * N;

  const MA* rp = rpairT + (size_t)n * T;

  int   a[ITEMS];
  float mv[ITEMS];
#pragma unroll
  for (int i = 0; i < ITEMS; i += 2) {           // 16B = 2 {m,a} pairs
    const ivec4 q = *(const ivec4*)(rp + t0 + i);
    mv[i]     = __int_as_float(q.x); a[i]     = q.y;
    mv[i + 1] = __int_as_float(q.z); a[i + 1] = q.w;
  }

  __shared__ int   s_last[CB];
  __shared__ int   s_cnt[CB];
  __shared__ float s_sum[CB];
  s_last[tid] = a[ITEMS - 1];
  __syncthreads();
  int prev = (tid > 0) ? s_last[tid - 1] : -1;   // argmax >= 0, so -1 != any

  bool keep[ITEMS];
  int   cnt = 0;
  float sum = 0.f;
#pragma unroll
  for (int i = 0; i < ITEMS; ++i) {
    const int t = t0 + i;
    keep[i] = (t < L) && (a[i] != blank) && (a[i] != prev);
    prev = a[i];
    cnt += keep[i] ? 1 : 0;
    sum += (t < L) ? mv[i] : 0.f;
  }

  s_cnt[tid] = cnt;
  s_sum[tid] = sum;
  __syncthreads();
  // inclusive Hillis-Steele scan (cnt) / reduction (sum rides along)
  for (int off = 1; off < CB; off <<= 1) {
    const int   c  = (tid >= off) ? s_cnt[tid - off] : 0;
    const float sv = (tid >= off) ? s_sum[tid - off] : 0.f;
    __syncthreads();
    s_cnt[tid] += c;
    s_sum[tid] += sv;
    __syncthreads();
  }
  if (tid == 0) {
    out_total[n] = s_sum[CB - 1];
    out_lens[n]  = (float)s_cnt[CB - 1];
  }

  // scatter kept tokens into compacted prefix (overwrites kernel-1 defaults;
  // cross-kernel ordering on the stream guarantees kernel 1 finished)
  int pos = s_cnt[tid] - cnt;                    // exclusive prefix
#pragma unroll
  for (int i = 0; i < ITEMS; ++i) {
    if (keep[i]) {
      out_paths[(size_t)pos * N + n] = (float)a[i];
      ++pos;
    }
  }
}

// Generic fallback (any T): two-pass structure, scalar pair reads.
__global__ __launch_bounds__(CB) void ctc_compact_kernel(
    const MA* __restrict__ rpairT,
    const int* __restrict__ in_lens, float* __restrict__ out,
    int T, int N, int V) {
  const int n = blockIdx.x;
  const int tid = threadIdx.x;
  const int L = in_lens[n];
  const int blank = V - 1;
  const int items = (T + CB - 1) / CB;
  const int t0 = tid * items;

  float* out_total = out;
  float* out_paths = out + N;
  float* out_lens  = out + N + (size_t)T * N;

  const MA* rp = rpairT + (size_t)n * T;

  int   cnt = 0;
  float sum = 0.f;
  int prev = (t0 > 0 && t0 <= T) ? rp[t0 - 1].a : -1;
  for (int i = 0; i < items; ++i) {
    const int t = t0 + i;
    if (t >= T) break;
    const int a = rp[t].a;
    const bool keep = (t < L) && (a != blank) && (t == 0 || a != prev);
    prev = a;
    cnt += keep ? 1 : 0;
    if (t < L) sum += rp[t].m;
  }

  __shared__ int   s_cnt[CB];
  __shared__ float s_sum[CB];
  s_cnt[tid] = cnt;
  s_sum[tid] = sum;
  __syncthreads();
  for (int off = 1; off < CB; off <<= 1) {
    const int   c  = (tid >= off) ? s_cnt[tid - off] : 0;
    const float sv = (tid >= off) ? s_sum[tid - off] : 0.f;
    __syncthreads();
    s_cnt[tid] += c;
    s_sum[tid] += sv;
    __syncthreads();
  }
  const int prefix = s_cnt[tid] - cnt;
  if (tid == 0) {
    out_total[n] = s_sum[CB - 1];
    out_lens[n]  = (float)s_cnt[CB - 1];
  }

  int pos = prefix;
  prev = (t0 > 0 && t0 <= T) ? rp[t0 - 1].a : -1;
  for (int i = 0; i < items; ++i) {
    const int t = t0 + i;
    if (t >= T) break;
    const int a = rp[t].a;
    const bool keep = (t < L) && (a != blank) && (t == 0 || a != prev);
    prev = a;
    if (keep) {
      out_paths[(size_t)pos * N + n] = (float)a;
      ++pos;
    }
  }
}

extern "C" void kernel_launch(void* const* d_in, const int* in_sizes, int n_in,
                              void* d_out, int out_size, void* d_ws, size_t ws_size,
                              hipStream_t stream) {
  const float* logits = (const float*)d_in[0];
  const int* in_lens  = (const int*)d_in[1];
  float* out = (float*)d_out;

  const int N = in_sizes[1];
  const int T = (out_size - 2 * N) / N;          // out = N + T*N + N
  const long long total = in_sizes[0];
  const int V = (int)(total / ((long long)T * N));
  const int rows = T * N;

  MA* rpairT = (MA*)d_ws;                        // rows * 8B
  float* out_paths = out + N;

  const int grid1 = (rows + 7) / 8;              // 4 waves x 2 rows per block

  if (V == 1024) {
    row_lse_kernel<4><<<grid1, 256, 0, stream>>>(logits, rpairT, out_paths, T, N, rows);
  } else if (V == 512) {
    row_lse_kernel<2><<<grid1, 256, 0, stream>>>(logits, rpairT, out_paths, T, N, rows);
  } else if (V == 2048) {
    row_lse_kernel<8><<<grid1, 256, 0, stream>>>(logits, rpairT, out_paths, T, N, rows);
  } else {
    const int gridg = (rows + 3) / 4;
    row_lse_generic<<<gridg, 256, 0, stream>>>(logits, rpairT, out_paths, T, N, V, rows);
  }

  if (T == CB * 8) {
    ctc_compact_fast<8><<<N, CB, 0, stream>>>(rpairT, in_lens, out, T, N, V);
  } else {
    ctc_compact_kernel<<<N, CB, 0, stream>>>(rpairT, in_lens, out, T, N, V);
  }
}